// Round 1
// baseline (1438.631 us; speedup 1.0000x reference)
//
#include <hip/hip_runtime.h>
#include <math.h>

#define NG  16384
#define NN  32
#define DD  128
#define RR  32
#define OO  64
#define HHH 256

// M[o][r] = sum_h Wl[o][h] * V[h][r]   (collapses readout@Wl.T into pooled@M.T)
__global__ void precompute_M_kernel(const float* __restrict__ Wl,
                                    const float* __restrict__ V,
                                    float* __restrict__ M) {
    int t = blockIdx.x * blockDim.x + threadIdx.x;   // 0..2047
    int o = t >> 5;
    int r = t & 31;
    float s = 0.f;
#pragma unroll 8
    for (int hh = 0; hh < HHH; ++hh)
        s = fmaf(Wl[o * HHH + hh], V[hh * RR + r], s);
    M[o * RR + r] = s;
}

__device__ __forceinline__ void fma4(float4& a, float s, const float4& w) {
    a.x = fmaf(s, w.x, a.x);
    a.y = fmaf(s, w.y, a.y);
    a.z = fmaf(s, w.z, a.z);
    a.w = fmaf(s, w.w, a.w);
}

typedef const float __attribute__((address_space(1))) gfloat;
typedef float       __attribute__((address_space(3))) lfloat;

// One wave per graph-quad, no block barriers in the hot loop.
// NEW vs 388us version: per-wave LDS DOUBLE-buffer with cross-graph prefetch
// and counted s_waitcnt vmcnt(4) (never 0 in steady state) — the chunk-(c+1)
// global_load_lds stays in flight while chunk c computes, hiding the ~900cy
// HBM latency under ~1100cy of FMAs (T3/T4 pattern). Stores are stashed in
// LDS and issued after the loop so the vmcnt queue contains ONLY the 8
// staging loads (4 current + 4 prefetch) -> vmcnt(4) is exact.
// h staging keeps the XOR-rotated-quad layout (element (n,sq) at float offset
// (n>>3)*256 + (n&7)*32 + ((sq-n)&7)*4) -> bank-conflict-free reads.
// LDS: 16K (W) + 32K (2 bufs x 4 waves) + 4K (scores) = 52KB -> 3 blocks/CU.
__global__ __launch_bounds__(256, 3)
void gin_main_kernel(const float* __restrict__ hsrc,
                     const float* __restrict__ W,
                     const float* __restrict__ M,
                     const float* __restrict__ bl,
                     float* __restrict__ out) {
    __shared__ float sW[DD * RR];          // [d][r] row-major, 16 KB
    __shared__ float sH[4][2][NN * 32];    // per-wave double-buffered 32x32 chunk
    __shared__ float sS[4][4 * 64];        // per-wave score stash (4 graphs x 64 o)

    const int tid  = threadIdx.x;
    const int lane = tid & 63;
    const int wv   = tid >> 6;

    const int rg = lane & 7;      // r-group: this lane covers r = rg*4 .. rg*4+3
    const int ng = lane >> 3;     // n-group: this lane covers n = ng, ng+8, ng+16, ng+24
    const int r0 = rg * 4;
    const int rowl = lane >> 3;   // staging row within 8-row group
    const int tq   = lane & 7;    // staging quad slot

    const int wave_global = blockIdx.x * 4 + wv;   // 0..4095
    const int g0 = wave_global * 4;
    const float* hg0 = hsrc + (size_t)g0 * (NN * DD);

    // prologue: stage (g0, chunk 0) into buf 0 — issued before the block barrier
    {
        float* dst = &sH[wv][0][0];
#pragma unroll
        for (int l = 0; l < 4; ++l) {
            const int row = l * 8 + rowl;
            const int sq  = (tq + row) & 7;            // XOR-rotate quads
            const float* gp = hg0 + row * DD + sq * 4;
            __builtin_amdgcn_global_load_lds((gfloat*)gp,
                                             (lfloat*)(dst + l * 256),
                                             16, 0, 0);
        }
    }

    {   // stage W once (straight copy — same [d][r] flat layout)
        const float4* Wv  = (const float4*)W;
        float4*       sWv = (float4*)sW;
#pragma unroll
        for (int k = 0; k < 4; ++k) sWv[tid + k * 256] = Wv[tid + k * 256];
    }
    __syncthreads();   // only block-wide barrier

    const float* pWb = sW + r0;
    const float blv = bl[lane];

#pragma unroll 1
    for (int gi = 0; gi < 4; ++gi) {
        const int g = g0 + gi;
        const float* hgc = hsrc + (size_t)g * (NN * DD);

        float4 acc0 = make_float4(0.f, 0.f, 0.f, 0.f);
        float4 acc1 = acc0, acc2 = acc0, acc3 = acc0;

#pragma unroll
        for (int c = 0; c < 4; ++c) {
            // prefetch chunk c+1 (possibly next graph's chunk 0) into buf (c+1)&1
            if (!((gi == 3) && (c == 3))) {
                const int cn = (c + 1) & 3;
                const float* hn = (c == 3) ? (hgc + NN * DD) : hgc;
                float* dst = &sH[wv][(c + 1) & 1][0];
#pragma unroll
                for (int l = 0; l < 4; ++l) {
                    const int row = l * 8 + rowl;
                    const int sq  = (tq + row) & 7;
                    const float* gp = hn + row * DD + cn * 32 + sq * 4;
                    __builtin_amdgcn_global_load_lds((gfloat*)gp,
                                                     (lfloat*)(dst + l * 256),
                                                     16, 0, 0);
                }
                // 8 loads in flight; wait for the 4 oldest (current chunk),
                // keep the 4 prefetch loads flying across the compute phase
                asm volatile("s_waitcnt vmcnt(4)" ::: "memory");
            } else {
                asm volatile("s_waitcnt vmcnt(0)" ::: "memory");
            }

            const float* ph = &sH[wv][c & 1][0] + ng * 32;
#pragma unroll
            for (int q = 0; q < 8; ++q) {
                const int d = c * 32 + q * 4;
                const int hq = ((q - ng) & 7) * 4;         // rotated quad offset
                float4 w0 = *(const float4*)(pWb + (d + 0) * RR);
                float4 w1 = *(const float4*)(pWb + (d + 1) * RR);
                float4 w2 = *(const float4*)(pWb + (d + 2) * RR);
                float4 w3 = *(const float4*)(pWb + (d + 3) * RR);
                float4 h0 = *(const float4*)(ph + 0 * 256 + hq);
                float4 h1 = *(const float4*)(ph + 1 * 256 + hq);
                float4 h2 = *(const float4*)(ph + 2 * 256 + hq);
                float4 h3 = *(const float4*)(ph + 3 * 256 + hq);
                fma4(acc0, h0.x, w0); fma4(acc0, h0.y, w1); fma4(acc0, h0.z, w2); fma4(acc0, h0.w, w3);
                fma4(acc1, h1.x, w0); fma4(acc1, h1.y, w1); fma4(acc1, h1.z, w2); fma4(acc1, h1.w, w3);
                fma4(acc2, h2.x, w0); fma4(acc2, h2.y, w1); fma4(acc2, h2.z, w2); fma4(acc2, h2.w, w3);
                fma4(acc3, h3.x, w0); fma4(acc3, h3.y, w1); fma4(acc3, h3.z, w2); fma4(acc3, h3.w, w3);
            }
        }

        // pooled[r] = prod over all 32 n: lane-local x4, then butterfly over ng lanes
        float4 p;
        p.x = acc0.x * acc1.x * acc2.x * acc3.x;
        p.y = acc0.y * acc1.y * acc2.y * acc3.y;
        p.z = acc0.z * acc1.z * acc2.z * acc3.z;
        p.w = acc0.w * acc1.w * acc2.w * acc3.w;
#pragma unroll
        for (int m = 8; m <= 32; m <<= 1) {
            p.x *= __shfl_xor(p.x, m);
            p.y *= __shfl_xor(p.y, m);
            p.z *= __shfl_xor(p.z, m);
            p.w *= __shfl_xor(p.w, m);
        }

        // score[o = lane] = bl[lane] + sum_r pooled[r] * M[lane][r]
        const float4* Mv = (const float4*)(M + lane * RR);
        float s = blv;
#pragma unroll
        for (int rq = 0; rq < 8; ++rq) {
            float4 pq;                       // pooled quad rq lives (a.o.) in lane rq
            pq.x = __shfl(p.x, rq);
            pq.y = __shfl(p.y, rq);
            pq.z = __shfl(p.z, rq);
            pq.w = __shfl(p.w, rq);
            float4 m4 = Mv[rq];
            s = fmaf(pq.x, m4.x, s);
            s = fmaf(pq.y, m4.y, s);
            s = fmaf(pq.z, m4.z, s);
            s = fmaf(pq.w, m4.w, s);
        }
        // stash in LDS; storing to global here would pollute the vmcnt queue
        sS[wv][gi * 64 + lane] = s;
    }

    // epilogue: drain scores to global (outside the pipelined loop)
#pragma unroll
    for (int gi = 0; gi < 4; ++gi) {
        out[(size_t)(g0 + gi) * OO + lane] = sS[wv][gi * 64 + lane];
    }
}

extern "C" void kernel_launch(void* const* d_in, const int* in_sizes, int n_in,
                              void* d_out, int out_size, void* d_ws, size_t ws_size,
                              hipStream_t stream) {
    const float* h  = (const float*)d_in[0];   // [16384,32,128]
    const float* W  = (const float*)d_in[1];   // [128,32]
    const float* V  = (const float*)d_in[2];   // [256,32]
    const float* Wl = (const float*)d_in[3];   // [64,256]
    const float* bl = (const float*)d_in[4];   // [64]
    float* out = (float*)d_out;                // [16384,64]
    float* M   = (float*)d_ws;                 // [64,32] scratch

    precompute_M_kernel<<<8, 256, 0, stream>>>(Wl, V, M);
    gin_main_kernel<<<1024, 256, 0, stream>>>(h, W, M, bl, out);
}

// Round 2
// 408.485 us; speedup vs baseline: 3.5219x; 3.5219x over previous
//
#include <hip/hip_runtime.h>
#include <math.h>

#define NG  16384
#define NN  32
#define DD  128
#define RR  32
#define OO  64
#define HHH 256

// M[o][r] = sum_h Wl[o][h] * V[h][r]   (collapses readout@Wl.T into pooled@M.T)
__global__ void precompute_M_kernel(const float* __restrict__ Wl,
                                    const float* __restrict__ V,
                                    float* __restrict__ M) {
    int t = blockIdx.x * blockDim.x + threadIdx.x;   // 0..2047
    int o = t >> 5;
    int r = t & 31;
    float s = 0.f;
#pragma unroll 8
    for (int hh = 0; hh < HHH; ++hh)
        s = fmaf(Wl[o * HHH + hh], V[hh * RR + r], s);
    M[o * RR + r] = s;
}

__device__ __forceinline__ void fma4(float4& a, float s, const float4& w) {
    a.x = fmaf(s, w.x, a.x);
    a.y = fmaf(s, w.y, a.y);
    a.z = fmaf(s, w.z, a.z);
    a.w = fmaf(s, w.w, a.w);
}

// R2 post-mortem: ALL h staging via global_load_lds removed. The DMA path
// was fetching ~5.5x the ideal bytes (FETCH 1.47GB vs 268MB ideal; the 388us
// baseline was equally overfetch-bound at 3.8TB/s), and the deeper in-flight
// DMA added 2.6GB of mystery WRITE traffic. Instead: each lane loads its 4
// rows' h-quads DIRECTLY with global_load_dwordx4. The 8 r-group lanes load
// identical addresses -> coalescer merges same-address lanes, L1 serves the
// cross-instr line reuse, so HBM fetch = unique lines = 16KB/graph exactly.
// No LDS for h, no inline asm, no barriers or vmcnt in the hot loop -- the
// compiler pipelines the loads; 3 waves/EU hides latency.
// W stays in LDS ([d][r] row-major): lanes rg=0..7 read banks rg*4..rg*4+3
// (broadcast across ng-duplicates) -> conflict-free.
__global__ __launch_bounds__(256, 3)
void gin_main_kernel(const float* __restrict__ hsrc,
                     const float* __restrict__ W,
                     const float* __restrict__ M,
                     const float* __restrict__ bl,
                     float* __restrict__ out) {
    __shared__ float sW[DD * RR];          // [d][r] row-major, 16 KB

    const int tid  = threadIdx.x;
    const int lane = tid & 63;
    const int wv   = tid >> 6;

    {   // stage W once (straight copy — same [d][r] flat layout)
        const float4* Wv  = (const float4*)W;
        float4*       sWv = (float4*)sW;
#pragma unroll
        for (int k = 0; k < 4; ++k) sWv[tid + k * 256] = Wv[tid + k * 256];
    }
    __syncthreads();   // only barrier in the kernel

    const int rg = lane & 7;      // r-group: this lane covers r = rg*4 .. rg*4+3
    const int ng = lane >> 3;     // n-group: this lane covers n = ng, ng+8, ng+16, ng+24
    const int r0 = rg * 4;
    const float* pWb = sW + r0;
    const float blv = bl[lane];

    const int wave_global = blockIdx.x * 4 + wv;   // 0..8191
    const int g0 = wave_global * 2;

#pragma unroll 1
    for (int gi = 0; gi < 2; ++gi) {
        const int g = g0 + gi;
        const float* hg  = hsrc + (size_t)g * (NN * DD);
        const float* hp0 = hg + (ng +  0) * DD;
        const float* hp1 = hg + (ng +  8) * DD;
        const float* hp2 = hg + (ng + 16) * DD;
        const float* hp3 = hg + (ng + 24) * DD;

        float4 acc0 = make_float4(0.f, 0.f, 0.f, 0.f);
        float4 acc1 = acc0, acc2 = acc0, acc3 = acc0;

#pragma unroll 2
        for (int dq = 0; dq < 32; ++dq) {
            const int d = dq * 4;
            float4 h0 = *(const float4*)(hp0 + d);
            float4 h1 = *(const float4*)(hp1 + d);
            float4 h2 = *(const float4*)(hp2 + d);
            float4 h3 = *(const float4*)(hp3 + d);
            float4 w0 = *(const float4*)(pWb + (d + 0) * RR);
            float4 w1 = *(const float4*)(pWb + (d + 1) * RR);
            float4 w2 = *(const float4*)(pWb + (d + 2) * RR);
            float4 w3 = *(const float4*)(pWb + (d + 3) * RR);
            fma4(acc0, h0.x, w0); fma4(acc0, h0.y, w1); fma4(acc0, h0.z, w2); fma4(acc0, h0.w, w3);
            fma4(acc1, h1.x, w0); fma4(acc1, h1.y, w1); fma4(acc1, h1.z, w2); fma4(acc1, h1.w, w3);
            fma4(acc2, h2.x, w0); fma4(acc2, h2.y, w1); fma4(acc2, h2.z, w2); fma4(acc2, h2.w, w3);
            fma4(acc3, h3.x, w0); fma4(acc3, h3.y, w1); fma4(acc3, h3.z, w2); fma4(acc3, h3.w, w3);
        }

        // pooled[r] = prod over all 32 n: lane-local x4, then butterfly over ng lanes
        float4 p;
        p.x = acc0.x * acc1.x * acc2.x * acc3.x;
        p.y = acc0.y * acc1.y * acc2.y * acc3.y;
        p.z = acc0.z * acc1.z * acc2.z * acc3.z;
        p.w = acc0.w * acc1.w * acc2.w * acc3.w;
#pragma unroll
        for (int m = 8; m <= 32; m <<= 1) {
            p.x *= __shfl_xor(p.x, m);
            p.y *= __shfl_xor(p.y, m);
            p.z *= __shfl_xor(p.z, m);
            p.w *= __shfl_xor(p.w, m);
        }

        // score[o = lane] = bl[lane] + sum_r pooled[r] * M[lane][r]
        const float4* Mv = (const float4*)(M + lane * RR);
        float s = blv;
#pragma unroll
        for (int rq = 0; rq < 8; ++rq) {
            float4 pq;                       // pooled quad rq lives (a.o.) in lane rq
            pq.x = __shfl(p.x, rq);
            pq.y = __shfl(p.y, rq);
            pq.z = __shfl(p.z, rq);
            pq.w = __shfl(p.w, rq);
            float4 m4 = Mv[rq];
            s = fmaf(pq.x, m4.x, s);
            s = fmaf(pq.y, m4.y, s);
            s = fmaf(pq.z, m4.z, s);
            s = fmaf(pq.w, m4.w, s);
        }
        out[(size_t)g * OO + lane] = s;
    }
}

extern "C" void kernel_launch(void* const* d_in, const int* in_sizes, int n_in,
                              void* d_out, int out_size, void* d_ws, size_t ws_size,
                              hipStream_t stream) {
    const float* h  = (const float*)d_in[0];   // [16384,32,128]
    const float* W  = (const float*)d_in[1];   // [128,32]
    const float* V  = (const float*)d_in[2];   // [256,32]
    const float* Wl = (const float*)d_in[3];   // [64,256]
    const float* bl = (const float*)d_in[4];   // [64]
    float* out = (float*)d_out;                // [16384,64]
    float* M   = (float*)d_ws;                 // [64,32] scratch

    precompute_M_kernel<<<8, 256, 0, stream>>>(Wl, V, M);
    gin_main_kernel<<<2048, 256, 0, stream>>>(h, W, M, bl, out);
}